// Round 8
// baseline (178.991 us; speedup 1.0000x reference)
//
#include <hip/hip_runtime.h>
#include <cstdint>
#include <cstddef>

#define NUM_HEADS 16
#define HEAD_DIM  64
#define WINDOW    512
#define D_MODEL   1024
#define BATCH     2
#define SEQ       2048
#define MTOT      (BATCH*SEQ)   // 4096
#define NQKV      (3*D_MODEL)   // 3072

typedef short bf16x8 __attribute__((ext_vector_type(8)));
typedef float f32x4  __attribute__((ext_vector_type(4)));

__device__ __forceinline__ f32x4 mfma16(bf16x8 a, bf16x8 b, f32x4 c) {
  return __builtin_amdgcn_mfma_f32_16x16x32_bf16(a, b, c, 0, 0, 0);
}

__device__ __forceinline__ unsigned short f2bf(float f) {
  unsigned int u = __float_as_uint(f);
  u += 0x7fffu + ((u >> 16) & 1u);
  return (unsigned short)(u >> 16);
}
__device__ __forceinline__ float bf2f(unsigned short b) {
  return __uint_as_float(((unsigned int)b) << 16);
}

// async global->LDS, 16B/lane; LDS dest = wave-uniform base + lane*16 (m104).
__device__ __forceinline__ void gld16(const unsigned short* g, unsigned short* l) {
  __builtin_amdgcn_global_load_lds(
      (const __attribute__((address_space(1))) unsigned int*)g,
      (__attribute__((address_space(3))) unsigned int*)l, 16, 0, 0);
}

// ---------------- fused prep: x->bf16 | qkv_w^T->bf16 | out_w^T->bf16 ----------------
__global__ __launch_bounds__(256) void prep_kernel(const float* __restrict__ x,
                                                   const float* __restrict__ qkv_w,
                                                   const float* __restrict__ out_w,
                                                   unsigned short* __restrict__ Xb,
                                                   unsigned short* __restrict__ Wq,
                                                   unsigned short* __restrict__ Wo) {
  __shared__ float tile[32][33];
  const int bid = blockIdx.x, t = threadIdx.x;
  if (bid < 4096) {
    int i = (bid * 256 + t) * 4;
    float4 v = *(const float4*)(x + i);
    ushort4 o;
    o.x = f2bf(v.x); o.y = f2bf(v.y); o.z = f2bf(v.z); o.w = f2bf(v.w);
    *(ushort4*)(Xb + i) = o;
    return;
  }
  const float* in; unsigned short* out; int R, C, bx, by;
  if (bid < 7168) { int b2 = bid - 4096; in = qkv_w; out = Wq; R = D_MODEL; C = NQKV; bx = b2 % 96; by = b2 / 96; }
  else            { int b2 = bid - 7168; in = out_w; out = Wo; R = D_MODEL; C = D_MODEL; bx = b2 & 31; by = b2 >> 5; }
  int tx = t & 31, ty = t >> 5;            // (32, 8)
  int c0 = bx * 32, r0 = by * 32;
#pragma unroll
  for (int i = 0; i < 32; i += 8)
    tile[ty + i][tx] = in[(size_t)(r0 + ty + i) * C + c0 + tx];
  __syncthreads();
#pragma unroll
  for (int i = 0; i < 32; i += 8)
    out[(size_t)(c0 + ty + i) * R + r0 + tx] = f2bf(tile[tx][ty + i]);
}

// ---------------- 3-stage pipelined bf16 GEMM mainloop, XOR-swizzled LDS -----------------
// A row-major (M,K), Bt row-major (N,K). Block tile (TI*32) x 128, 4 waves 2x2.
// SWAP=false: acc = C (row=m,col=n). SWAP=true: acc = C^T (row=n,col=m).
// Distance-2 prefetch into 3 LDS buffers; barrier waits vmcnt(N) so the newest
// prefetch stays in flight ACROSS the barrier. K templated -> full unroll.
template<int TI, bool SWAP, int K>
__device__ __forceinline__ void gemm_mainloop_p3(const unsigned short* __restrict__ A,
                                                 const unsigned short* __restrict__ Bt,
                                                 int m0, int n0,
                                                 unsigned short* sA, unsigned short* sB,
                                                 f32x4 (&acc)[TI][4]) {
  const int t = threadIdx.x;
  const int lane = t & 63, wave = t >> 6;
  const int wm = wave >> 1, wn = wave & 1;
  const int lhi = lane >> 4, llo = lane & 15;
  f32x4 zero = {0.f, 0.f, 0.f, 0.f};
#pragma unroll
  for (int i = 0; i < TI; ++i)
#pragma unroll
    for (int j = 0; j < 4; ++j) acc[i][j] = zero;

  const int cswz = (((t & 3) ^ ((t >> 3) & 3)) << 3);   // swizzled k-chunk for staging
  const unsigned short* gA = A  + (size_t)(m0 + (t >> 2)) * K + cswz;
  const unsigned short* gB = Bt + (size_t)(n0 + (t >> 2)) * K + cswz;
  const size_t rowskip = (size_t)64 * K;
  const int ldsT = t * 8;
  const int rsw  = (lhi ^ ((llo >> 1) & 3)) * 8;        // swizzled chunk for frag reads
  const int aoff = (wm * (TI * 16) + llo) * 32 + rsw;
  const int boff = (wn * 64 + llo) * 32 + rsw;
  constexpr int ABUF = TI * 1024;                       // ushorts per A buffer
  constexpr int nIter = K / 32;

  auto stage = [&](int it2) {
    unsigned short* dA = sA + (it2 % 3) * ABUF;
    unsigned short* dB = sB + (it2 % 3) * 4096;
    const int kk = it2 * 32;
    gld16(gA + kk, dA + ldsT);
    if (TI == 4) gld16(gA + kk + rowskip, dA + ldsT + 2048);
    gld16(gB + kk, dB + ldsT);
    gld16(gB + kk + rowskip, dB + ldsT + 2048);
  };

  stage(0);
  stage(1);
#pragma unroll
  for (int it = 0; it < nIter; ++it) {
    // wait for tile `it` (oldest loads); keep tile `it+1` (newest) in flight
    if (it + 1 < nIter) {
      if (TI == 4) asm volatile("s_waitcnt vmcnt(4)\n\ts_barrier" ::: "memory");
      else         asm volatile("s_waitcnt vmcnt(3)\n\ts_barrier" ::: "memory");
    } else {
      asm volatile("s_waitcnt vmcnt(0)\n\ts_barrier" ::: "memory");
    }
    if (it + 2 < nIter) stage(it + 2);
    const unsigned short* cA = sA + (it % 3) * ABUF;
    const unsigned short* cB = sB + (it % 3) * 4096;
    bf16x8 af[TI], bfr[4];
#pragma unroll
    for (int i = 0; i < TI; ++i) af[i]  = *(const bf16x8*)(cA + aoff + i * 512);
#pragma unroll
    for (int j = 0; j < 4; ++j)  bfr[j] = *(const bf16x8*)(cB + boff + j * 512);
#pragma unroll
    for (int i = 0; i < TI; ++i)
#pragma unroll
      for (int j = 0; j < 4; ++j)
        acc[i][j] = SWAP ? mfma16(bfr[j], af[i], acc[i][j])
                         : mfma16(af[i], bfr[j], acc[i][j]);
  }
}

// ---------------- QKV projection GEMM (all blocks: SWAP / C^T accumulator) ---------------
// Lane holds 4 CONSECUTIVE d-values (row=n) for one s (col=m) -> 8B ushort4 stores.
// n0 < 2048: Q/K to (bh,s,d) — 16 store instrs/thread (was 64 scalar 2B).
// n0 >= 2048: V direct to V^T (bh,d,s).
__global__ __launch_bounds__(256) void qkv_gemm_kernel(const unsigned short* __restrict__ Xb,
                                                       const unsigned short* __restrict__ Wt,
                                                       const float* __restrict__ bias,
                                                       unsigned short* __restrict__ Qw,
                                                       unsigned short* __restrict__ Kw,
                                                       unsigned short* __restrict__ Vtw) {
  __shared__ __align__(16) unsigned short sA[3][128 * 32];
  __shared__ __align__(16) unsigned short sB[3][128 * 32];
  f32x4 acc[4][4];
  const int m0 = blockIdx.y * 128, n0 = blockIdx.x * 128;
  const int t = threadIdx.x, lane = t & 63, wave = t >> 6;
  const int wm = wave >> 1, wn = wave & 1, lhi = lane >> 4, llo = lane & 15;

  gemm_mainloop_p3<4, true, D_MODEL>(Xb, Wt, m0, n0, sA[0], sB[0], acc);

  if (n0 < 2048) {
    const int c = n0 >> 10;     // block-uniform: Q or K
    unsigned short* __restrict__ Dst = (c == 0) ? Qw : Kw;
    const float qs = (c == 0) ? 0.125f : 1.0f;
#pragma unroll
    for (int ti = 0; ti < 4; ++ti) {
      int m = m0 + wm * 64 + ti * 16 + llo;   // s-dim (col of C^T)
      int b = m >> 11, s = m & 2047;
#pragma unroll
      for (int tj = 0; tj < 4; ++tj) {
        int nb = n0 + wn * 64 + tj * 16 + lhi * 4;   // d-base (row of C^T), 4-aligned
        float4 bv = *(const float4*)(bias + nb);
        int h = (nb >> 6) & 15, dbase = nb & 63;
        int bh = b * 16 + h;
        ushort4 pk;
        pk.x = f2bf((acc[ti][tj][0] + bv.x) * qs);
        pk.y = f2bf((acc[ti][tj][1] + bv.y) * qs);
        pk.z = f2bf((acc[ti][tj][2] + bv.z) * qs);
        pk.w = f2bf((acc[ti][tj][3] + bv.w) * qs);
        *(ushort4*)(Dst + ((size_t)(bh * 2048 + s)) * 64 + dbase) = pk;
      }
    }
  } else {
#pragma unroll
    for (int ti = 0; ti < 4; ++ti) {
      int m = m0 + wm * 64 + ti * 16 + llo;   // s-dim (col of C^T)
      int b = m >> 11, s = m & 2047;
#pragma unroll
      for (int tj = 0; tj < 4; ++tj) {
        int nb = n0 + wn * 64 + tj * 16 + lhi * 4;   // d-base (row of C^T), 4-aligned
        float4 bv = *(const float4*)(bias + nb);
        int h = (nb >> 6) & 15, dbase = nb & 63;
        int bh = b * 16 + h;
        float bvr[4] = {bv.x, bv.y, bv.z, bv.w};
#pragma unroll
        for (int r = 0; r < 4; ++r)
          Vtw[(size_t)(bh * 64 + dbase + r) * 2048 + s] = f2bf(acc[ti][tj][r] + bvr[r]);
      }
    }
  }
}

// ---------------- flash sliding-window attention (S^T, 512 threads, 3-stage K/V) ---------
__global__ __launch_bounds__(512) void attn_kernel(const unsigned short* __restrict__ Qw,
                                                   const unsigned short* __restrict__ Kw,
                                                   const unsigned short* __restrict__ Vtw,
                                                   unsigned short* __restrict__ AO) {
  __shared__ __align__(16) unsigned short sK[3][64 * 64];  // (key,d), XOR-swizzled chunks
  __shared__ __align__(16) unsigned short sV[3][64 * 64];  // (d,key), XOR-swizzled chunks
  __shared__ __align__(16) unsigned short sP[8][16 * 72];  // per-wave P (query,key), pad 72
  const int t = threadIdx.x, lane = t & 63, wave = t >> 6;  // wave 0..7
  const int lhi = lane >> 4, llo = lane & 15;
  const int bh = blockIdx.x;                 // bh%8 -> XCD; q-tiles of bh share L2
  const int q0 = (15 - blockIdx.y) << 7;     // heaviest q-tiles dispatch first
  const unsigned short* Qb = Qw  + (size_t)bh * 2048 * 64;
  const unsigned short* Kb = Kw  + (size_t)bh * 2048 * 64;
  const unsigned short* Vb = Vtw + (size_t)bh * 64 * 2048;

  const int qw = q0 + wave * 16;             // this wave's query base
  const int qrow = qw + llo;                 // this lane's query (column of S^T)
  bf16x8 qf0 = *(const bf16x8*)(Qb + (size_t)qrow * 64 + lhi * 8);
  bf16x8 qf1 = *(const bf16x8*)(Qb + (size_t)qrow * 64 + 32 + lhi * 8);

  const int srow = t >> 3;                   // 512 threads cover a full 64x64 bf16 tile
  const int scol = ((t & 7) ^ (srow & 7)) * 8;   // XOR-swizzled staging chunk
  const int cpos  = (lhi ^ (llo & 7)) * 8;       // swizzled chunk for frag reads
  const int cposx = cpos ^ 32;                   // chunk c^4

  float m_i = -1e30f, l_i = 0.f;
  f32x4 o[4];
  f32x4 zero = {0.f, 0.f, 0.f, 0.f};
#pragma unroll
  for (int td = 0; td < 4; ++td) o[td] = zero;

  const int kt_lo = (q0 > 511) ? ((q0 - 511) >> 6) : 0;
  const int kt_hi = (q0 + 127) >> 6;         // every block has >= 2 k-tiles

  auto stageKV = [&](int j) {
    const int k0 = j << 6;
    unsigned short* dK = sK[j % 3];
    unsigned short* dV = sV[j % 3];
    gld16(Kb + (size_t)(k0 + srow) * 64 + scol, dK + t * 8);
    gld16(Vb + (size_t)srow * 2048 + k0 + scol, dV + t * 8);
  };

  stageKV(kt_lo);
  stageKV(kt_lo + 1);

  for (int kt = kt_lo; kt <= kt_hi; ++kt) {
    // wait for tile kt (2 oldest); keep tile kt+1 (2 newest) in flight across barrier
    if (kt < kt_hi) asm volatile("s_waitcnt vmcnt(2)\n\ts_barrier" ::: "memory");
    else            asm volatile("s_waitcnt vmcnt(0)\n\ts_barrier" ::: "memory");
    if (kt + 2 <= kt_hi) stageKV(kt + 2);
    const int k0 = kt << 6;
    // per-wave uniform skip: wave queries qw..qw+15, window union [qw-511, qw+15]
    if (k0 > qw + 15 || k0 + 63 < qw - (WINDOW - 1)) continue;  // no barrier inside

    const unsigned short* bK = sK[kt % 3];
    const unsigned short* bV = sV[kt % 3];

    // S^T tiles: row = key (tk*16 + lhi*4 + r), col = query (llo)
    f32x4 st[4];
#pragma unroll
    for (int tk = 0; tk < 4; ++tk) {
      const unsigned short* kr = bK + (tk * 16 + llo) * 64;
      bf16x8 kf0 = *(const bf16x8*)(kr + cpos);
      bf16x8 kf1 = *(const bf16x8*)(kr + cposx);
      f32x4 z = zero;
      z = mfma16(kf0, qf0, z);
      z = mfma16(kf1, qf1, z);
      st[tk] = z;
    }

    // mask + in-lane max over 16 keys, then 2-shfl cross-quad reduce
    const int kb = k0 + lhi * 4;
    float mx = -1e30f;
#pragma unroll
    for (int tk = 0; tk < 4; ++tk)
#pragma unroll
      for (int r = 0; r < 4; ++r) {
        int key = kb + tk * 16 + r;
        bool ok = (key <= qrow) && (qrow - key < WINDOW);
        float s = ok ? st[tk][r] : -1e30f;
        st[tk][r] = s;
        mx = fmaxf(mx, s);
      }
    mx = fmaxf(mx, __shfl_xor(mx, 16));
    mx = fmaxf(mx, __shfl_xor(mx, 32));
    float mn = fmaxf(m_i, mx);
    float a  = __expf(m_i - mn);  // fully-masked tile garbage wiped by a=0 on next real tile
    float rs = 0.f;
    unsigned short* pw = &sP[wave][llo * 72];
#pragma unroll
    for (int tk = 0; tk < 4; ++tk) {
      ushort4 pb;
      pb.x = f2bf(__expf(st[tk][0] - mn));
      pb.y = f2bf(__expf(st[tk][1] - mn));
      pb.z = f2bf(__expf(st[tk][2] - mn));
      pb.w = f2bf(__expf(st[tk][3] - mn));
      *(ushort4*)(pw + tk * 16 + lhi * 4) = pb;
      rs += bf2f(pb.x) + bf2f(pb.y) + bf2f(pb.z) + bf2f(pb.w);
    }
    rs += __shfl_xor(rs, 16);
    rs += __shfl_xor(rs, 32);
    l_i = l_i * a + rs;
    m_i = mn;

    float aR[4];
#pragma unroll
    for (int r = 0; r < 4; ++r) aR[r] = __shfl(a, lhi * 4 + r);
#pragma unroll
    for (int td = 0; td < 4; ++td)
#pragma unroll
      for (int r = 0; r < 4; ++r) o[td][r] *= aR[r];

    // O += P V (same-wave LDS write->read ordering, no barrier needed)
    bf16x8 pf0 = *(const bf16x8*)(pw + lhi * 8);
    bf16x8 pf1 = *(const bf16x8*)(pw + 32 + lhi * 8);
#pragma unroll
    for (int td = 0; td < 4; ++td) {
      const unsigned short* vr = bV + (td * 16 + llo) * 64;
      bf16x8 vf0 = *(const bf16x8*)(vr + cpos);
      bf16x8 vf1 = *(const bf16x8*)(vr + cposx);
      o[td] = mfma16(pf0, vf0, o[td]);
      o[td] = mfma16(pf1, vf1, o[td]);
    }
  }

  float lR[4];
#pragma unroll
  for (int r = 0; r < 4; ++r) lR[r] = 1.f / __shfl(l_i, lhi * 4 + r);
  const int b = bh >> 4, h = bh & 15;
#pragma unroll
  for (int td = 0; td < 4; ++td)
#pragma unroll
    for (int r = 0; r < 4; ++r) {
      int qr = q0 + wave * 16 + lhi * 4 + r;
      AO[(size_t)(b * 2048 + qr) * 1024 + h * 64 + td * 16 + llo] = f2bf(o[td][r] * lR[r]);
    }
}

// ---------------- output projection GEMM (64x128 tile -> 512 blocks, 2/CU) ---------------
__global__ __launch_bounds__(256) void out_gemm_kernel(const unsigned short* __restrict__ AO,
                                                       const unsigned short* __restrict__ Wt,
                                                       const float* __restrict__ bias,
                                                       float* __restrict__ out) {
  __shared__ __align__(16) unsigned short sA[3][64 * 32];
  __shared__ __align__(16) unsigned short sB[3][128 * 32];
  f32x4 acc[2][4];
  const int m0 = blockIdx.y * 64, n0 = blockIdx.x * 128;
  gemm_mainloop_p3<2, false, D_MODEL>(AO, Wt, m0, n0, sA[0], sB[0], acc);

  const int t = threadIdx.x, lane = t & 63, wave = t >> 6;
  const int wm = wave >> 1, wn = wave & 1, lhi = lane >> 4, llo = lane & 15;
#pragma unroll
  for (int ti = 0; ti < 2; ++ti)
#pragma unroll
    for (int tj = 0; tj < 4; ++tj) {
      int n = n0 + wn * 64 + tj * 16 + llo;
      float bv = bias[n];
#pragma unroll
      for (int r = 0; r < 4; ++r) {
        int m = m0 + wm * 32 + ti * 16 + lhi * 4 + r;
        out[(size_t)m * D_MODEL + n] = acc[ti][tj][r] + bv;
      }
    }
}

extern "C" void kernel_launch(void* const* d_in, const int* in_sizes, int n_in,
                              void* d_out, int out_size, void* d_ws, size_t ws_size,
                              hipStream_t stream) {
  const float* x      = (const float*)d_in[0];
  const float* qkv_w  = (const float*)d_in[1];
  const float* qkv_b  = (const float*)d_in[2];
  const float* out_w  = (const float*)d_in[3];
  const float* out_b  = (const float*)d_in[4];
  float* out = (float*)d_out;
  char* ws = (char*)d_ws;

  // workspace layout (48 MB total)
  unsigned short* Xb  = (unsigned short*)(ws);                          // 8 MB  x bf16
  unsigned short* Wq  = (unsigned short*)(ws + ((size_t)8  << 20));     // 6 MB  qkv_w^T bf16
  unsigned short* Wo  = (unsigned short*)(ws + ((size_t)14 << 20));     // 2 MB  out_w^T bf16
  unsigned short* Qw  = (unsigned short*)(ws + ((size_t)16 << 20));     // 8 MB  Q (bh,s,d)*1/8
  unsigned short* Kw  = (unsigned short*)(ws + ((size_t)24 << 20));     // 8 MB  K (bh,s,d)
  unsigned short* Vtw = (unsigned short*)(ws + ((size_t)32 << 20));     // 8 MB  V^T (bh,d,s)
  unsigned short* AO  = (unsigned short*)(ws + ((size_t)40 << 20));     // 8 MB  attn out (m,hd)

  prep_kernel<<<8192, 256, 0, stream>>>(x, qkv_w, out_w, Xb, Wq, Wo);
  qkv_gemm_kernel<<<dim3(NQKV / 128, MTOT / 128), 256, 0, stream>>>(Xb, Wq, qkv_b, Qw, Kw, Vtw);
  attn_kernel<<<dim3(BATCH * NUM_HEADS, SEQ / 128), 512, 0, stream>>>(Qw, Kw, Vtw, AO);
  out_gemm_kernel<<<dim3(D_MODEL / 128, MTOT / 64), 256, 0, stream>>>(AO, Wo, out_b, out);
}

// Round 9
// 163.827 us; speedup vs baseline: 1.0926x; 1.0926x over previous
//
#include <hip/hip_runtime.h>
#include <cstdint>
#include <cstddef>

#define NUM_HEADS 16
#define HEAD_DIM  64
#define WINDOW    512
#define D_MODEL   1024
#define BATCH     2
#define SEQ       2048
#define MTOT      (BATCH*SEQ)   // 4096
#define NQKV      (3*D_MODEL)   // 3072

typedef short bf16x8 __attribute__((ext_vector_type(8)));
typedef float f32x4  __attribute__((ext_vector_type(4)));

__device__ __forceinline__ f32x4 mfma16(bf16x8 a, bf16x8 b, f32x4 c) {
  return __builtin_amdgcn_mfma_f32_16x16x32_bf16(a, b, c, 0, 0, 0);
}

__device__ __forceinline__ unsigned short f2bf(float f) {
  unsigned int u = __float_as_uint(f);
  u += 0x7fffu + ((u >> 16) & 1u);
  return (unsigned short)(u >> 16);
}
__device__ __forceinline__ float bf2f(unsigned short b) {
  return __uint_as_float(((unsigned int)b) << 16);
}

// async global->LDS, 16B/lane; LDS dest = wave-uniform base + lane*16 (m104).
__device__ __forceinline__ void gld16(const unsigned short* g, unsigned short* l) {
  __builtin_amdgcn_global_load_lds(
      (const __attribute__((address_space(1))) unsigned int*)g,
      (__attribute__((address_space(3))) unsigned int*)l, 16, 0, 0);
}

// ---------------- fused prep: x->bf16 | qkv_w^T->bf16 | out_w^T->bf16 ----------------
__global__ __launch_bounds__(256) void prep_kernel(const float* __restrict__ x,
                                                   const float* __restrict__ qkv_w,
                                                   const float* __restrict__ out_w,
                                                   unsigned short* __restrict__ Xb,
                                                   unsigned short* __restrict__ Wq,
                                                   unsigned short* __restrict__ Wo) {
  __shared__ float tile[32][33];
  const int bid = blockIdx.x, t = threadIdx.x;
  if (bid < 4096) {
    int i = (bid * 256 + t) * 4;
    float4 v = *(const float4*)(x + i);
    ushort4 o;
    o.x = f2bf(v.x); o.y = f2bf(v.y); o.z = f2bf(v.z); o.w = f2bf(v.w);
    *(ushort4*)(Xb + i) = o;
    return;
  }
  const float* in; unsigned short* out; int R, C, bx, by;
  if (bid < 7168) { int b2 = bid - 4096; in = qkv_w; out = Wq; R = D_MODEL; C = NQKV; bx = b2 % 96; by = b2 / 96; }
  else            { int b2 = bid - 7168; in = out_w; out = Wo; R = D_MODEL; C = D_MODEL; bx = b2 & 31; by = b2 >> 5; }
  int tx = t & 31, ty = t >> 5;            // (32, 8)
  int c0 = bx * 32, r0 = by * 32;
#pragma unroll
  for (int i = 0; i < 32; i += 8)
    tile[ty + i][tx] = in[(size_t)(r0 + ty + i) * C + c0 + tx];
  __syncthreads();
#pragma unroll
  for (int i = 0; i < 32; i += 8)
    out[(size_t)(c0 + ty + i) * R + r0 + tx] = f2bf(tile[tx][ty + i]);
}

// ---------------- 512-thread 3-stage pipelined GEMM mainloop, XOR-swizzled LDS -----------
// A row-major (M,K), Bt row-major (N,K). Block tile 128x128, 8 waves in 4x2:
// wave tile 32(m) x 64(n) = 2x4 MFMA grid -> 6 waves/SIMD at 3 blocks/CU (2x the
// 256-thread version's TLP; r3-r8 showed the GEMM is latency-bound, all pipes <25%).
// Staging: 1 gld16/thread/array covers a full 128x32 stage -> 2 loads/stage;
// barrier waits vmcnt(2) keeping the newest stage in flight across it.
// SWAP=false: acc = C (row=m,col=n). SWAP=true: acc = C^T (row=n,col=m).
template<bool SWAP, int K>
__device__ __forceinline__ void gemm_mainloop512(const unsigned short* __restrict__ A,
                                                 const unsigned short* __restrict__ Bt,
                                                 int m0, int n0,
                                                 unsigned short* sA, unsigned short* sB,
                                                 f32x4 (&acc)[2][4]) {
  const int t = threadIdx.x;
  const int lane = t & 63, wave = t >> 6;
  const int wr = wave >> 1, wc = wave & 1;   // 4x2 wave grid
  const int lhi = lane >> 4, llo = lane & 15;
  f32x4 zero = {0.f, 0.f, 0.f, 0.f};
#pragma unroll
  for (int i = 0; i < 2; ++i)
#pragma unroll
    for (int j = 0; j < 4; ++j) acc[i][j] = zero;

  const int cswz = (((t & 3) ^ ((t >> 3) & 3)) << 3);   // swizzled k-chunk for staging
  const unsigned short* gA = A  + (size_t)(m0 + (t >> 2)) * K + cswz;
  const unsigned short* gB = Bt + (size_t)(n0 + (t >> 2)) * K + cswz;
  const int ldsT = t * 8;
  const int rsw  = (lhi ^ ((llo >> 1) & 3)) * 8;        // swizzled chunk for frag reads
  const int aoff = (wr * 32 + llo) * 32 + rsw;
  const int boff = (wc * 64 + llo) * 32 + rsw;
  constexpr int nIter = K / 32;

  auto stage = [&](int s) {
    unsigned short* dA = sA + (s % 3) * 4096;
    unsigned short* dB = sB + (s % 3) * 4096;
    gld16(gA + s * 32, dA + ldsT);
    gld16(gB + s * 32, dB + ldsT);
  };

  stage(0);
  stage(1);
#pragma unroll
  for (int it = 0; it < nIter; ++it) {
    // wait tile `it` (2 oldest loads); keep tile `it+1` (2 newest) in flight
    if (it + 1 < nIter) asm volatile("s_waitcnt vmcnt(2)\n\ts_barrier" ::: "memory");
    else                asm volatile("s_waitcnt vmcnt(0)\n\ts_barrier" ::: "memory");
    if (it + 2 < nIter) stage(it + 2);
    const unsigned short* cA = sA + (it % 3) * 4096;
    const unsigned short* cB = sB + (it % 3) * 4096;
    bf16x8 af[2], bfr[4];
#pragma unroll
    for (int i = 0; i < 2; ++i) af[i]  = *(const bf16x8*)(cA + aoff + i * 512);
#pragma unroll
    for (int j = 0; j < 4; ++j)  bfr[j] = *(const bf16x8*)(cB + boff + j * 512);
#pragma unroll
    for (int i = 0; i < 2; ++i)
#pragma unroll
      for (int j = 0; j < 4; ++j)
        acc[i][j] = SWAP ? mfma16(bfr[j], af[i], acc[i][j])
                         : mfma16(af[i], bfr[j], acc[i][j]);
  }
}

// ---------------- QKV projection GEMM (512 threads) --------------------------------------
// n0 < 2048: Q/K, normal orientation, coalesced (bh,s,d) stores (r7-proven form).
// n0 >= 2048: V, transposed accumulator, DIRECT V^T (bh,d,s) stores.
__global__ __launch_bounds__(512, 6) void qkv_gemm_kernel(const unsigned short* __restrict__ Xb,
                                                          const unsigned short* __restrict__ Wt,
                                                          const float* __restrict__ bias,
                                                          unsigned short* __restrict__ Qw,
                                                          unsigned short* __restrict__ Kw,
                                                          unsigned short* __restrict__ Vtw) {
  __shared__ __align__(16) unsigned short sA[3][128 * 32];
  __shared__ __align__(16) unsigned short sB[3][128 * 32];
  f32x4 acc[2][4];
  const int m0 = blockIdx.y * 128, n0 = blockIdx.x * 128;
  const int t = threadIdx.x, lane = t & 63, wave = t >> 6;
  const int wr = wave >> 1, wc = wave & 1, lhi = lane >> 4, llo = lane & 15;

  if (n0 < 2048) {
    gemm_mainloop512<false, D_MODEL>(Xb, Wt, m0, n0, sA[0], sB[0], acc);
    const int c = n0 >> 10;     // block-uniform: Q or K
    unsigned short* __restrict__ Dst = (c == 0) ? Qw : Kw;
    const float qs = (c == 0) ? 0.125f : 1.0f;
#pragma unroll
    for (int ti = 0; ti < 2; ++ti) {
#pragma unroll
      for (int tj = 0; tj < 4; ++tj) {
        int n = n0 + wc * 64 + tj * 16 + llo;
        float bv = bias[n];
        int h = (n >> 6) & 15, d = n & 63;
#pragma unroll
        for (int r = 0; r < 4; ++r) {
          int m = m0 + wr * 32 + ti * 16 + lhi * 4 + r;
          int b = m >> 11, s = m & 2047;
          int bh = b * 16 + h;
          Dst[((size_t)(bh * 2048 + s)) * 64 + d] = f2bf((acc[ti][tj][r] + bv) * qs);
        }
      }
    }
  } else {
    gemm_mainloop512<true, D_MODEL>(Xb, Wt, m0, n0, sA[0], sB[0], acc);
#pragma unroll
    for (int ti = 0; ti < 2; ++ti) {
      int m = m0 + wr * 32 + ti * 16 + llo;   // s-dim (col of C^T)
      int b = m >> 11, s = m & 2047;
#pragma unroll
      for (int tj = 0; tj < 4; ++tj) {
        int nb = n0 + wc * 64 + tj * 16 + lhi * 4;   // d-base (row of C^T), 4-aligned
        float4 bv = *(const float4*)(bias + nb);
        int h = (nb >> 6) & 15, dbase = nb & 63;
        int bh = b * 16 + h;
        float bvr[4] = {bv.x, bv.y, bv.z, bv.w};
#pragma unroll
        for (int r = 0; r < 4; ++r)
          Vtw[(size_t)(bh * 64 + dbase + r) * 2048 + s] = f2bf(acc[ti][tj][r] + bvr[r]);
      }
    }
  }
}

// ---------------- flash sliding-window attention (S^T, 512 threads, 3-stage K/V) ---------
__global__ __launch_bounds__(512) void attn_kernel(const unsigned short* __restrict__ Qw,
                                                   const unsigned short* __restrict__ Kw,
                                                   const unsigned short* __restrict__ Vtw,
                                                   unsigned short* __restrict__ AO) {
  __shared__ __align__(16) unsigned short sK[3][64 * 64];  // (key,d), XOR-swizzled chunks
  __shared__ __align__(16) unsigned short sV[3][64 * 64];  // (d,key), XOR-swizzled chunks
  __shared__ __align__(16) unsigned short sP[8][16 * 72];  // per-wave P (query,key), pad 72
  const int t = threadIdx.x, lane = t & 63, wave = t >> 6;  // wave 0..7
  const int lhi = lane >> 4, llo = lane & 15;
  const int bh = blockIdx.x;                 // bh%8 -> XCD; q-tiles of bh share L2
  const int q0 = (15 - blockIdx.y) << 7;     // heaviest q-tiles dispatch first
  const unsigned short* Qb = Qw  + (size_t)bh * 2048 * 64;
  const unsigned short* Kb = Kw  + (size_t)bh * 2048 * 64;
  const unsigned short* Vb = Vtw + (size_t)bh * 64 * 2048;

  const int qw = q0 + wave * 16;             // this wave's query base
  const int qrow = qw + llo;                 // this lane's query (column of S^T)
  bf16x8 qf0 = *(const bf16x8*)(Qb + (size_t)qrow * 64 + lhi * 8);
  bf16x8 qf1 = *(const bf16x8*)(Qb + (size_t)qrow * 64 + 32 + lhi * 8);

  const int srow = t >> 3;                   // 512 threads cover a full 64x64 bf16 tile
  const int scol = ((t & 7) ^ (srow & 7)) * 8;   // XOR-swizzled staging chunk
  const int cpos  = (lhi ^ (llo & 7)) * 8;       // swizzled chunk for frag reads
  const int cposx = cpos ^ 32;                   // chunk c^4

  float m_i = -1e30f, l_i = 0.f;
  f32x4 o[4];
  f32x4 zero = {0.f, 0.f, 0.f, 0.f};
#pragma unroll
  for (int td = 0; td < 4; ++td) o[td] = zero;

  const int kt_lo = (q0 > 511) ? ((q0 - 511) >> 6) : 0;
  const int kt_hi = (q0 + 127) >> 6;         // every block has >= 2 k-tiles

  auto stageKV = [&](int j) {
    const int k0 = j << 6;
    unsigned short* dK = sK[j % 3];
    unsigned short* dV = sV[j % 3];
    gld16(Kb + (size_t)(k0 + srow) * 64 + scol, dK + t * 8);
    gld16(Vb + (size_t)srow * 2048 + k0 + scol, dV + t * 8);
  };

  stageKV(kt_lo);
  stageKV(kt_lo + 1);

  for (int kt = kt_lo; kt <= kt_hi; ++kt) {
    // wait for tile kt (2 oldest); keep tile kt+1 (2 newest) in flight across barrier
    if (kt < kt_hi) asm volatile("s_waitcnt vmcnt(2)\n\ts_barrier" ::: "memory");
    else            asm volatile("s_waitcnt vmcnt(0)\n\ts_barrier" ::: "memory");
    if (kt + 2 <= kt_hi) stageKV(kt + 2);
    const int k0 = kt << 6;
    // per-wave uniform skip: wave queries qw..qw+15, window union [qw-511, qw+15]
    if (k0 > qw + 15 || k0 + 63 < qw - (WINDOW - 1)) continue;  // no barrier inside

    const unsigned short* bK = sK[kt % 3];
    const unsigned short* bV = sV[kt % 3];

    // S^T tiles: row = key (tk*16 + lhi*4 + r), col = query (llo)
    f32x4 st[4];
#pragma unroll
    for (int tk = 0; tk < 4; ++tk) {
      const unsigned short* kr = bK + (tk * 16 + llo) * 64;
      bf16x8 kf0 = *(const bf16x8*)(kr + cpos);
      bf16x8 kf1 = *(const bf16x8*)(kr + cposx);
      f32x4 z = zero;
      z = mfma16(kf0, qf0, z);
      z = mfma16(kf1, qf1, z);
      st[tk] = z;
    }

    // wave-uniform interior fast path: all 16 keysx queries valid -> skip masking
    const bool interior = (k0 >= qw - (WINDOW - 1 - 15)) && (k0 + 63 <= qw);
    const int kb = k0 + lhi * 4;
    float mx = -1e30f;
    if (interior) {
#pragma unroll
      for (int tk = 0; tk < 4; ++tk)
#pragma unroll
        for (int r = 0; r < 4; ++r) mx = fmaxf(mx, st[tk][r]);
    } else {
#pragma unroll
      for (int tk = 0; tk < 4; ++tk)
#pragma unroll
        for (int r = 0; r < 4; ++r) {
          int key = kb + tk * 16 + r;
          bool ok = (key <= qrow) && (qrow - key < WINDOW);
          float s = ok ? st[tk][r] : -1e30f;
          st[tk][r] = s;
          mx = fmaxf(mx, s);
        }
    }
    mx = fmaxf(mx, __shfl_xor(mx, 16));
    mx = fmaxf(mx, __shfl_xor(mx, 32));
    float mn = fmaxf(m_i, mx);
    float a  = __expf(m_i - mn);  // fully-masked tile garbage wiped by a=0 on next real tile
    float rs = 0.f;
    unsigned short* pw = &sP[wave][llo * 72];
#pragma unroll
    for (int tk = 0; tk < 4; ++tk) {
      ushort4 pb;
      pb.x = f2bf(__expf(st[tk][0] - mn));
      pb.y = f2bf(__expf(st[tk][1] - mn));
      pb.z = f2bf(__expf(st[tk][2] - mn));
      pb.w = f2bf(__expf(st[tk][3] - mn));
      *(ushort4*)(pw + tk * 16 + lhi * 4) = pb;
      rs += bf2f(pb.x) + bf2f(pb.y) + bf2f(pb.z) + bf2f(pb.w);
    }
    rs += __shfl_xor(rs, 16);
    rs += __shfl_xor(rs, 32);
    l_i = l_i * a + rs;
    m_i = mn;

    float aR[4];
#pragma unroll
    for (int r = 0; r < 4; ++r) aR[r] = __shfl(a, lhi * 4 + r);
#pragma unroll
    for (int td = 0; td < 4; ++td)
#pragma unroll
      for (int r = 0; r < 4; ++r) o[td][r] *= aR[r];

    // O += P V (same-wave LDS write->read ordering, no barrier needed)
    bf16x8 pf0 = *(const bf16x8*)(pw + lhi * 8);
    bf16x8 pf1 = *(const bf16x8*)(pw + 32 + lhi * 8);
#pragma unroll
    for (int td = 0; td < 4; ++td) {
      const unsigned short* vr = bV + (td * 16 + llo) * 64;
      bf16x8 vf0 = *(const bf16x8*)(vr + cpos);
      bf16x8 vf1 = *(const bf16x8*)(vr + cposx);
      o[td] = mfma16(pf0, vf0, o[td]);
      o[td] = mfma16(pf1, vf1, o[td]);
    }
  }

  float lR[4];
#pragma unroll
  for (int r = 0; r < 4; ++r) lR[r] = 1.f / __shfl(l_i, lhi * 4 + r);
  const int b = bh >> 4, h = bh & 15;
#pragma unroll
  for (int td = 0; td < 4; ++td)
#pragma unroll
    for (int r = 0; r < 4; ++r) {
      int qr = q0 + wave * 16 + lhi * 4 + r;
      AO[(size_t)(b * 2048 + qr) * 1024 + h * 64 + td * 16 + llo] = f2bf(o[td][r] * lR[r]);
    }
}

// ---------------- output projection GEMM (128x128 tile, 512 threads) ---------------------
__global__ __launch_bounds__(512, 2) void out_gemm_kernel(const unsigned short* __restrict__ AO,
                                                          const unsigned short* __restrict__ Wt,
                                                          const float* __restrict__ bias,
                                                          float* __restrict__ out) {
  __shared__ __align__(16) unsigned short sA[3][128 * 32];
  __shared__ __align__(16) unsigned short sB[3][128 * 32];
  f32x4 acc[2][4];
  const int m0 = blockIdx.y * 128, n0 = blockIdx.x * 128;
  gemm_mainloop512<false, D_MODEL>(AO, Wt, m0, n0, sA[0], sB[0], acc);

  const int t = threadIdx.x, lane = t & 63, wave = t >> 6;
  const int wr = wave >> 1, wc = wave & 1, lhi = lane >> 4, llo = lane & 15;
#pragma unroll
  for (int ti = 0; ti < 2; ++ti)
#pragma unroll
    for (int tj = 0; tj < 4; ++tj) {
      int n = n0 + wc * 64 + tj * 16 + llo;
      float bv = bias[n];
#pragma unroll
      for (int r = 0; r < 4; ++r) {
        int m = m0 + wr * 32 + ti * 16 + lhi * 4 + r;
        out[(size_t)m * D_MODEL + n] = acc[ti][tj][r] + bv;
      }
    }
}

extern "C" void kernel_launch(void* const* d_in, const int* in_sizes, int n_in,
                              void* d_out, int out_size, void* d_ws, size_t ws_size,
                              hipStream_t stream) {
  const float* x      = (const float*)d_in[0];
  const float* qkv_w  = (const float*)d_in[1];
  const float* qkv_b  = (const float*)d_in[2];
  const float* out_w  = (const float*)d_in[3];
  const float* out_b  = (const float*)d_in[4];
  float* out = (float*)d_out;
  char* ws = (char*)d_ws;

  // workspace layout (48 MB total)
  unsigned short* Xb  = (unsigned short*)(ws);                          // 8 MB  x bf16
  unsigned short* Wq  = (unsigned short*)(ws + ((size_t)8  << 20));     // 6 MB  qkv_w^T bf16
  unsigned short* Wo  = (unsigned short*)(ws + ((size_t)14 << 20));     // 2 MB  out_w^T bf16
  unsigned short* Qw  = (unsigned short*)(ws + ((size_t)16 << 20));     // 8 MB  Q (bh,s,d)*1/8
  unsigned short* Kw  = (unsigned short*)(ws + ((size_t)24 << 20));     // 8 MB  K (bh,s,d)
  unsigned short* Vtw = (unsigned short*)(ws + ((size_t)32 << 20));     // 8 MB  V^T (bh,d,s)
  unsigned short* AO  = (unsigned short*)(ws + ((size_t)40 << 20));     // 8 MB  attn out (m,hd)

  prep_kernel<<<8192, 256, 0, stream>>>(x, qkv_w, out_w, Xb, Wq, Wo);
  qkv_gemm_kernel<<<dim3(NQKV / 128, MTOT / 128), 512, 0, stream>>>(Xb, Wq, qkv_b, Qw, Kw, Vtw);
  attn_kernel<<<dim3(BATCH * NUM_HEADS, SEQ / 128), 512, 0, stream>>>(Qw, Kw, Vtw, AO);
  out_gemm_kernel<<<dim3(D_MODEL / 128, MTOT / 128), 512, 0, stream>>>(AO, Wo, out_b, out);
}